// Round 1
// baseline (445.350 us; speedup 1.0000x reference)
//
#include <hip/hip_runtime.h>
#include <hip/hip_bf16.h>

#define L2E 1.4426950408889634f

#if defined(__has_builtin)
#if __has_builtin(__builtin_amdgcn_exp2f)
#define EXP2(x) __builtin_amdgcn_exp2f(x)
#else
#define EXP2(x) exp2f(x)
#endif
#else
#define EXP2(x) exp2f(x)
#endif

typedef __attribute__((ext_vector_type(8))) short bf16x8;
typedef __attribute__((ext_vector_type(4))) float f32x4;

__device__ __forceinline__ void gld_lds16(const void* g, void* l) {
  __builtin_amdgcn_global_load_lds(
      (const __attribute__((address_space(1))) void*)g,
      (__attribute__((address_space(3))) void*)l, 16, 0, 0);
}

__device__ __forceinline__ unsigned bf16rne(float f) {
  unsigned u = __float_as_uint(f);
  return (u + 0x7fffu + ((u >> 16) & 1u)) >> 16;
}

// Kernel A: L2-normalize embedding table -> packed bf16 (2 per uint32).
__global__ __launch_bounds__(256) void knrm_norm(const float* __restrict__ emb,
                                                 unsigned* __restrict__ embN) {
  const int lane = threadIdx.x & 63;
  int gw = blockIdx.x * 4 + (threadIdx.x >> 6);
  const int nW = gridDim.x * 4;
  for (int r = gw; r < 50000; r += nW) {
    float2 v = *(const float2*)(emb + (size_t)r * 128 + lane * 2);
    float ss = v.x * v.x + v.y * v.y;
#pragma unroll
    for (int m = 1; m < 64; m <<= 1) ss += __shfl_xor(ss, m, 64);
    float sc = 1.0f / fmaxf(sqrtf(ss), 1e-12f);
    embN[(size_t)r * 64 + lane] = bf16rne(v.x * sc) | (bf16rne(v.y * sc) << 16);
  }
}

// Kernel B: per batch item: gather q(64) + d(256) bf16 rows to LDS,
// mm^T via mfma_f32_16x16x32_bf16, factorized 20-kernel accumulation,
// exact-match kernel via integer token compare, then fused MLP.
__global__ __launch_bounds__(256, 3) void knrm_main(
    const int* __restrict__ query, const int* __restrict__ doc,
    const unsigned* __restrict__ embN,
    const float* __restrict__ W1, const float* __restrict__ b1,
    const float* __restrict__ W2, const float* __restrict__ b2,
    const float* __restrict__ W3, const float* __restrict__ b3,
    float* __restrict__ out) {
  __shared__ __align__(16) char qtile[64 * 256];    // 16KB, reused as kmbuf later
  __shared__ __align__(16) char dtile[128 * 256];   // 32KB (one half of docs)
  __shared__ int qtok[64];
  __shared__ int dtok[256];
  __shared__ float km2[4][21];
  __shared__ float kmv[21];
  __shared__ float x1[10];
  __shared__ float x2[5];
  float* kmbuf = (float*)qtile;  // [64][21] raw kernel sums (overlay, post-compute)

  const int b = blockIdx.x;
  const int tid = threadIdx.x;
  const int w = tid >> 6;
  const int lane = tid & 63;
  const int lo = lane & 15, hi = lane >> 4;
  const char* embB = (const char*)embN;  // 256 B per vocab row (128 bf16)

  // ---- token staging (plain LDS writes) ----
  if (tid < 64) qtok[tid] = query[b * 64 + tid];
  dtok[tid] = doc[b * 256 + tid];

  // ---- stage q tile (wave w: rows 16w..16w+15) + d half 0 (rows 32w..32w+31)
  // LDS layout: row-major 256B rows, 16B slots XOR-swizzled: phys_slot = log_slot ^ (row&7).
  // global_load_lds writes linearly (base + lane*16), so we pre-swizzle the SOURCE slot.
#pragma unroll
  for (int it = 0; it < 4; ++it) {
    int r = w * 16 + it * 4 + hi;
    int tok = query[b * 64 + r];
    int slot = lo ^ (r & 7);
    gld_lds16(embB + (size_t)tok * 256 + slot * 16, qtile + (w * 16 + it * 4) * 256);
  }
#pragma unroll
  for (int it = 0; it < 8; ++it) {
    int rl = w * 32 + it * 4 + hi;  // local dtile row = doc 0..127
    int tok = doc[b * 256 + rl];
    int slot = lo ^ (rl & 7);
    gld_lds16(embB + (size_t)tok * 256 + slot * 16, dtile + (w * 32 + it * 4) * 256);
  }
  asm volatile("s_waitcnt vmcnt(0)" ::: "memory");
  __syncthreads();

  // ---- load Q fragments (B-operand: col = lo = q, k = 8*hi+e), once ----
  bf16x8 bq[4];
#pragma unroll
  for (int kk = 0; kk < 4; ++kk) {
    int slot = (kk * 4 + hi) ^ (lo & 7);
    bq[kk] = *(const bf16x8*)(qtile + (w * 16 + lo) * 256 + slot * 16);
  }

  float acc20[20];
#pragma unroll
  for (int j = 0; j < 20; ++j) acc20[j] = 0.0f;

  const float cA = -50.0f * L2E;   // for |v|*(95-50|v|) exponent (log2 domain)
  const float cB = 95.0f * L2E;
  const float cR = -10.0f * L2E;

#pragma unroll 1
  for (int h = 0; h < 2; ++h) {
    if (h == 1) {
      __syncthreads();  // everyone done reading dtile half 0
#pragma unroll
      for (int it = 0; it < 8; ++it) {
        int rl = w * 32 + it * 4 + hi;
        int tok = doc[b * 256 + 128 + rl];
        int slot = lo ^ (rl & 7);
        gld_lds16(embB + (size_t)tok * 256 + slot * 16, dtile + (w * 32 + it * 4) * 256);
      }
      asm volatile("s_waitcnt vmcnt(0)" ::: "memory");
      __syncthreads();
    }
#pragma unroll
    for (int dr = 0; dr < 8; ++dr) {
      f32x4 mm = {0.0f, 0.0f, 0.0f, 0.0f};
#pragma unroll
      for (int kk = 0; kk < 4; ++kk) {
        int row = dr * 16 + lo;  // doc row (A-operand: row = lo, k = 8*hi+e)
        int slot = (kk * 4 + hi) ^ (lo & 7);
        bf16x8 a = *(const bf16x8*)(dtile + row * 256 + slot * 16);
        mm = __builtin_amdgcn_mfma_f32_16x16x32_bf16(a, bq[kk], mm, 0, 0, 0);
      }
      // mm[e]: doc = 16*dr + 4*hi + e (this half), q = w*16 + lo
#pragma unroll
      for (int e = 0; e < 4; ++e) {
        float v = mm[e];
        float av = fabsf(v);
        float m1 = fmaf(cA, av, cB);       // (95 - 50|v|)*log2e
        float eA = EXP2(m1 * av);          // p at the max-end mu (0.95*sign)
        float r = EXP2(cR * av);           // ratio exp(-10|v|), <= 1
        bool pos = (v >= 0.0f);
        float qq[20];
        qq[0] = eA;
#pragma unroll
        for (int i = 1; i < 20; ++i) qq[i] = qq[i - 1] * r;
#pragma unroll
        for (int j = 0; j < 20; ++j) acc20[j] += pos ? qq[19 - j] : qq[j];
      }
    }
  }

  // ---- exact-match kernel via integer equality (lane covers docs 64*hi..64*hi+63)
  int myq = qtok[w * 16 + lo];
  int cnt = 0;
#pragma unroll 16
  for (int i = 0; i < 64; ++i) cnt += (dtok[hi * 64 + i] == myq) ? 1 : 0;

  // ---- reduce over hi (lanes 16,32 apart share same q) ----
#pragma unroll
  for (int j = 0; j < 20; ++j) {
    acc20[j] += __shfl_xor(acc20[j], 16, 64);
    acc20[j] += __shfl_xor(acc20[j], 32, 64);
  }
  cnt += __shfl_xor(cnt, 16, 64);
  cnt += __shfl_xor(cnt, 32, 64);

  // qtile LDS is dead (bq in regs since before half-0 compute) -> overlay kmbuf
  if (hi == 0) {
    int q = w * 16 + lo;
#pragma unroll
    for (int j = 0; j < 20; ++j) kmbuf[q * 21 + j] = acc20[j];
    kmbuf[q * 21 + 20] = (float)cnt;
  }
  __syncthreads();

  // ---- km[j] = sum_q log1p(C_j * rawsum) ----
  if (tid < 84) {
    int j = tid % 21, c = tid / 21;
    float Cj = 1.0f;
    if (j < 20) {
      float mu = -0.95f + 0.1f * (float)j;
      Cj = EXP2(cA * mu * mu);  // exp(-50*mu^2)
    }
    float s = 0.0f;
    for (int q = 0; q < 16; ++q) s += log1pf(Cj * kmbuf[(c * 16 + q) * 21 + j]);
    km2[c][j] = s;
  }
  __syncthreads();
  if (tid < 21)
    kmv[tid] = fmaxf(km2[0][tid] + km2[1][tid] + km2[2][tid] + km2[3][tid], 0.0f);
  __syncthreads();
  if (tid < 10) {
    float s = b1[tid];
    for (int j = 0; j < 21; ++j) s = fmaf(W1[tid * 21 + j], kmv[j], s);
    x1[tid] = fmaxf(s, 0.0f);
  }
  __syncthreads();
  if (tid < 5) {
    float s = b2[tid];
    for (int i = 0; i < 10; ++i) s = fmaf(W2[tid * 10 + i], x1[i], s);
    x2[tid] = s;
  }
  __syncthreads();
  if (tid == 0) {
    float s = b3[0];
    for (int i = 0; i < 5; ++i) s = fmaf(W3[i], x2[i], s);
    out[b] = s;
  }
}

extern "C" void kernel_launch(void* const* d_in, const int* in_sizes, int n_in,
                              void* d_out, int out_size, void* d_ws, size_t ws_size,
                              hipStream_t stream) {
  const int* query = (const int*)d_in[0];
  const int* doc = (const int*)d_in[1];
  const float* emb = (const float*)d_in[2];
  const float* W1 = (const float*)d_in[3];
  const float* b1 = (const float*)d_in[4];
  const float* W2 = (const float*)d_in[5];
  const float* b2 = (const float*)d_in[6];
  const float* W3 = (const float*)d_in[7];
  const float* b3 = (const float*)d_in[8];
  float* out = (float*)d_out;
  unsigned* embN = (unsigned*)d_ws;  // 50000*64 uints = 12.8 MB bf16 table

  hipLaunchKernelGGL(knrm_norm, dim3(1024), dim3(256), 0, stream, emb, embN);
  hipLaunchKernelGGL(knrm_main, dim3(1024), dim3(256), 0, stream, query, doc, embN,
                     W1, b1, W2, b2, W3, b3, out);
}